// Round 9
// baseline (286.625 us; speedup 1.0000x reference)
//
#include <hip/hip_runtime.h>
#include <math.h>

#define IN_F 128
#define OUT_F 32
#define HEADS 4
#define HC 128  // HEADS*OUT_F
#define NEG_SLOPE 0.2f
#define LOG2E 1.44269504088896f

__device__ __forceinline__ unsigned short f2bf(float f) {  // RNE fp32->bf16
    unsigned u = __float_as_uint(f);
    u += 0x7FFFu + ((u >> 16) & 1u);
    return (unsigned short)(u >> 16);
}

// ---------------------------------------------------------------------------
// 1) Projection GEMM: [N x 128] @ [128 x 256] -> xl(bf16) | xr(fp32).
//    32-node tile / 256-thread block.  32 col-groups x 8 row-groups; each
//    thread: 4 rows x 8 cols, the 8 cols as two DENSE 4-col groups (cb,
//    cb+64) -> W lane stride stays 16B (R6's 32B-stride trap avoided) while
//    LDS reads halve vs R5 (4 ds_read_b128 per k4 instead of 8).
//    Also zero-inits deg|fill|cursor (replaces memset launch).
// ---------------------------------------------------------------------------
__global__ void __launch_bounds__(256)
proj_kernel(const float* __restrict__ x,
            const float* __restrict__ Wl,
            const float* __restrict__ Wr,
            unsigned short* __restrict__ xlb,
            float* __restrict__ xr, int N,
            int* __restrict__ zero_region, int zero_cnt) {
    __shared__ float xs[32 * IN_F];  // 16 KB
    const int tid = threadIdx.x;
    const int n0 = blockIdx.x * 32;
    const int rows = min(32, N - n0);

    // fold the CSR zero-init into this kernel (one launch saved)
    const int gz = blockIdx.x * 256 + tid;
    if (gz < zero_cnt) zero_region[gz] = 0;

    const float4* x4 = (const float4*)(x + (size_t)n0 * IN_F);
    float4* xs4 = (float4*)xs;
    const int nval4 = rows * (IN_F / 4);
#pragma unroll
    for (int q = 0; q < 4; ++q) {
        const int idx = q * 256 + tid;
        xs4[idx] = (idx < nval4) ? x4[idx] : make_float4(0.f, 0.f, 0.f, 0.f);
    }
    __syncthreads();

    const int cg = tid & 31;   // column group
    const int rg = tid >> 5;   // row group: 4 consecutive rows
    const float* Wp;
    int cb;
    const bool isL = (cg < 16);
    if (isL) { Wp = Wl; cb = cg * 4; }
    else     { Wp = Wr; cb = (cg - 16) * 4; }

    float4 acc0[4], acc1[4];
#pragma unroll
    for (int r = 0; r < 4; ++r) {
        acc0[r] = make_float4(0.f, 0.f, 0.f, 0.f);
        acc1[r] = make_float4(0.f, 0.f, 0.f, 0.f);
    }

    const float* xrow = xs + rg * 4 * IN_F;
#pragma unroll 4
    for (int k = 0; k < IN_F; k += 4) {
        float4 wa[4], wb[4];
#pragma unroll
        for (int kk = 0; kk < 4; ++kk) {
            wa[kk] = *(const float4*)&Wp[(k + kk) * HC + cb];        // dense 16B lanes
            wb[kk] = *(const float4*)&Wp[(k + kk) * HC + cb + 64];   // dense 16B lanes
        }
#pragma unroll
        for (int r = 0; r < 4; ++r) {
            const float4 xv = *(const float4*)&xrow[r * IN_F + k];  // LDS b128 (4/k4)
            acc0[r].x += xv.x * wa[0].x; acc0[r].y += xv.x * wa[0].y;
            acc0[r].z += xv.x * wa[0].z; acc0[r].w += xv.x * wa[0].w;
            acc1[r].x += xv.x * wb[0].x; acc1[r].y += xv.x * wb[0].y;
            acc1[r].z += xv.x * wb[0].z; acc1[r].w += xv.x * wb[0].w;
            acc0[r].x += xv.y * wa[1].x; acc0[r].y += xv.y * wa[1].y;
            acc0[r].z += xv.y * wa[1].z; acc0[r].w += xv.y * wa[1].w;
            acc1[r].x += xv.y * wb[1].x; acc1[r].y += xv.y * wb[1].y;
            acc1[r].z += xv.y * wb[1].z; acc1[r].w += xv.y * wb[1].w;
            acc0[r].x += xv.z * wa[2].x; acc0[r].y += xv.z * wa[2].y;
            acc0[r].z += xv.z * wa[2].z; acc0[r].w += xv.z * wa[2].w;
            acc1[r].x += xv.z * wb[2].x; acc1[r].y += xv.z * wb[2].y;
            acc1[r].z += xv.z * wb[2].z; acc1[r].w += xv.z * wb[2].w;
            acc0[r].x += xv.w * wa[3].x; acc0[r].y += xv.w * wa[3].y;
            acc0[r].z += xv.w * wa[3].z; acc0[r].w += xv.w * wa[3].w;
            acc1[r].x += xv.w * wb[3].x; acc1[r].y += xv.w * wb[3].y;
            acc1[r].z += xv.w * wb[3].z; acc1[r].w += xv.w * wb[3].w;
        }
    }

#pragma unroll
    for (int r = 0; r < 4; ++r) {
        const int rr = rg * 4 + r;
        if (rr >= rows) continue;
        if (isL) {  // bf16-packed xl
            ushort4 p0, p1;
            p0.x = f2bf(acc0[r].x); p0.y = f2bf(acc0[r].y);
            p0.z = f2bf(acc0[r].z); p0.w = f2bf(acc0[r].w);
            p1.x = f2bf(acc1[r].x); p1.y = f2bf(acc1[r].y);
            p1.z = f2bf(acc1[r].z); p1.w = f2bf(acc1[r].w);
            *(ushort4*)&xlb[(size_t)(n0 + rr) * HC + cb] = p0;
            *(ushort4*)&xlb[(size_t)(n0 + rr) * HC + cb + 64] = p1;
        } else {    // fp32 xr
            *(float4*)&xr[(size_t)(n0 + rr) * HC + cb] = acc0[r];
            *(float4*)&xr[(size_t)(n0 + rr) * HC + cb + 64] = acc1[r];
        }
    }
}

// ---------------------------------------------------------------------------
// 2) CSR build
// ---------------------------------------------------------------------------
__global__ void hist_kernel(const int* __restrict__ ei, int* __restrict__ deg,
                            int E0, int Etot) {
    const int t = blockIdx.x * blockDim.x + threadIdx.x;
    if (t >= Etot) return;
    const int dst = (t < E0) ? ei[E0 + t] : (t - E0);
    atomicAdd(&deg[dst], 1);
}

__global__ void alloc_kernel(const int* __restrict__ deg,
                             int* __restrict__ start,
                             unsigned int* __restrict__ cursor, int N) {
    __shared__ int sc[256];
    __shared__ int base_s;
    const int tid = threadIdx.x;
    const int n = blockIdx.x * 256 + tid;
    const int d = (n < N) ? deg[n] : 0;
    sc[tid] = d;
    __syncthreads();
#pragma unroll
    for (int off = 1; off < 256; off <<= 1) {
        int v = (tid >= off) ? sc[tid - off] : 0;
        __syncthreads();
        sc[tid] += v;
        __syncthreads();
    }
    if (tid == 255) base_s = (int)atomicAdd(cursor, (unsigned int)sc[255]);
    __syncthreads();
    if (n < N) start[n] = base_s + sc[tid] - d;  // exclusive
}

__global__ void scatter_kernel(const int* __restrict__ ei,
                               const int* __restrict__ start,
                               int* __restrict__ fill,
                               int* __restrict__ esrc,
                               int E0, int Etot) {
    const int t = blockIdx.x * blockDim.x + threadIdx.x;
    if (t >= Etot) return;
    int src, dst;
    if (t < E0) { src = ei[t]; dst = ei[E0 + t]; }
    else        { src = dst = t - E0; }
    const int pos = start[dst] + atomicAdd(&fill[dst], 1);
    esrc[pos] = src;
}

// ---------------------------------------------------------------------------
// 3) Fused attention + softmax + aggregation.  One wave per node; lane l owns
//    channels (2l, 2l+1).  xl gathered as bf16x2 (one dword/lane, SGPR-base
//    address via readfirstlane — src is wave-uniform).  DPP 4-stage reduce +
//    ds_swizzle row broadcast.  No segment-max (validated R4-R8).
// ---------------------------------------------------------------------------
template <int CTRL>
__device__ __forceinline__ float dpp_add(float v) {
    const int t = __builtin_amdgcn_update_dpp(
        0, __float_as_int(v), CTRL, 0xF, 0xF, true);
    return v + __int_as_float(t);
}

__device__ __forceinline__ float row_sum_bcast(float c) {
    c = dpp_add<0x111>(c);  // row_shr:1
    c = dpp_add<0x112>(c);  // row_shr:2
    c = dpp_add<0x114>(c);  // row_shr:4
    c = dpp_add<0x118>(c);  // row_shr:8 -> lane15 of each 16-row = row sum
    return __int_as_float(
        __builtin_amdgcn_ds_swizzle(__float_as_int(c), 0x01F0));  // bcast lane15
}

__global__ void __launch_bounds__(256)
fused_agg_kernel(const unsigned short* __restrict__ xlb,
                 const float* __restrict__ xr,
                 const float* __restrict__ att,
                 const float* __restrict__ bias,
                 const int* __restrict__ esrc,
                 const int* __restrict__ start,
                 const int* __restrict__ deg,
                 float* __restrict__ out, int N, int EtotM1) {
    __shared__ int les_all[4][68];
    const int wid = threadIdx.x >> 6;
    const int lane = threadIdx.x & 63;
    const int n = blockIdx.x * 4 + wid;
    if (n >= N) return;
    int* les = les_all[wid];

    const int ch = lane * 2;  // channel pair; head = lane>>4 = DPP row
    const float2 xr2 = *(const float2*)&xr[(size_t)n * HC + ch];
    const float2 at2 = *(const float2*)&att[ch];
    const float au0 = at2.x * LOG2E, au1 = at2.y * LOG2E;
    const float an0 = au0 * NEG_SLOPE, an1 = au1 * NEG_SLOPE;
    const int s0 = start[n];
    const int d = deg[n];                      // >= 1 (self-loop)

    float sum = 0.f, ax = 0.f, ay = 0.f;

    for (int jb = 0; jb < d; jb += 64) {
        const int cnt = min(64, d - jb);
        les[lane] = esrc[min(s0 + jb + lane, EtotM1)];  // clamped: valid id
        if (lane < 4) les[64 + lane] = 0;               // pad for prefetch

        const int sA0 = __builtin_amdgcn_readfirstlane(les[0]);
        const int sB0 = __builtin_amdgcn_readfirstlane(les[1]);
        unsigned pkA = *(const unsigned*)&xlb[(size_t)sA0 * HC + ch];
        unsigned pkB = *(const unsigned*)&xlb[(size_t)sB0 * HC + ch];

        int j = 0;
        for (; j + 1 < cnt; j += 2) {
            const int sC = __builtin_amdgcn_readfirstlane(les[j + 2]);
            const int sD = __builtin_amdgcn_readfirstlane(les[j + 3]);
            const unsigned pkC = *(const unsigned*)&xlb[(size_t)sC * HC + ch];
            const unsigned pkD = *(const unsigned*)&xlb[(size_t)sD * HC + ch];

            // edge A
            {
                const float vx = __uint_as_float(pkA << 16);
                const float vy = __uint_as_float(pkA & 0xFFFF0000u);
                const float sx = vx + xr2.x;
                const float sy = vy + xr2.y;
                float c = ((sx > 0.f) ? au0 : an0) * sx;
                c = fmaf(((sy > 0.f) ? au1 : an1), sy, c);
                const float p = exp2f(row_sum_bcast(c));
                sum += p;
                ax = fmaf(p, vx, ax);
                ay = fmaf(p, vy, ay);
            }
            // edge B
            {
                const float vx = __uint_as_float(pkB << 16);
                const float vy = __uint_as_float(pkB & 0xFFFF0000u);
                const float sx = vx + xr2.x;
                const float sy = vy + xr2.y;
                float c = ((sx > 0.f) ? au0 : an0) * sx;
                c = fmaf(((sy > 0.f) ? au1 : an1), sy, c);
                const float p = exp2f(row_sum_bcast(c));
                sum += p;
                ax = fmaf(p, vx, ax);
                ay = fmaf(p, vy, ay);
            }
            pkA = pkC; pkB = pkD;
        }
        if (j < cnt) {  // tail edge
            const float vx = __uint_as_float(pkA << 16);
            const float vy = __uint_as_float(pkA & 0xFFFF0000u);
            const float sx = vx + xr2.x;
            const float sy = vy + xr2.y;
            float c = ((sx > 0.f) ? au0 : an0) * sx;
            c = fmaf(((sy > 0.f) ? au1 : an1), sy, c);
            const float p = exp2f(row_sum_bcast(c));
            sum += p;
            ax = fmaf(p, vx, ax);
            ay = fmaf(p, vy, ay);
        }
    }
    const float inv = 1.f / (sum + 1e-16f);
    const float2 b2 = *(const float2*)&bias[ch];
    float2 o;
    o.x = fmaf(ax, inv, b2.x);
    o.y = fmaf(ay, inv, b2.y);
    *(float2*)&out[(size_t)n * HC + ch] = o;
}

// ---------------------------------------------------------------------------
extern "C" void kernel_launch(void* const* d_in, const int* in_sizes, int n_in,
                              void* d_out, int out_size, void* d_ws, size_t ws_size,
                              hipStream_t stream) {
    const float* x    = (const float*)d_in[0];
    const int*   ei   = (const int*)d_in[1];   // harness delivers int inputs as int32
    const float* Wl   = (const float*)d_in[2];
    const float* Wr   = (const float*)d_in[3];
    const float* att  = (const float*)d_in[4];
    const float* bias = (const float*)d_in[5];
    float* out        = (float*)d_out;

    const int N    = in_sizes[0] / IN_F;   // 50000
    const int E0   = in_sizes[1] / 2;      // 800000
    const int Etot = E0 + N;               // 850000

    char* base = (char*)d_ws;
    unsigned short* xlb = (unsigned short*)base; base += (size_t)N * HC * sizeof(unsigned short);
    float* xr   = (float*)base;        base += (size_t)N * HC * sizeof(float);
    int*   esrc = (int*)base;          base += (size_t)Etot * sizeof(int);
    // contiguous zero region: deg | fill | cursor
    int*   deg  = (int*)base;          base += (size_t)N * sizeof(int);
    int*   fill = (int*)base;          base += (size_t)N * sizeof(int);
    unsigned int* cursor = (unsigned int*)base; base += sizeof(unsigned int);
    int*   strt = (int*)base;

    proj_kernel<<<(N + 31) / 32, 256, 0, stream>>>(x, Wl, Wr, xlb, xr, N,
                                                   deg, 2 * N + 1);
    hist_kernel<<<(Etot + 255) / 256, 256, 0, stream>>>(ei, deg, E0, Etot);
    alloc_kernel<<<(N + 255) / 256, 256, 0, stream>>>(deg, strt, cursor, N);
    scatter_kernel<<<(Etot + 255) / 256, 256, 0, stream>>>(ei, strt, fill, esrc, E0, Etot);

    fused_agg_kernel<<<(N + 3) / 4, 256, 0, stream>>>(xlb, xr, att, bias, esrc, strt, deg,
                                                      out, N, Etot - 1);
}

// Round 10
// 281.567 us; speedup vs baseline: 1.0180x; 1.0180x over previous
//
#include <hip/hip_runtime.h>
#include <math.h>

#define IN_F 128
#define OUT_F 32
#define HEADS 4
#define HC 128  // HEADS*OUT_F
#define NEG_SLOPE 0.2f
#define LOG2E 1.44269504088896f

__device__ __forceinline__ unsigned short f2bf(float f) {  // RNE fp32->bf16
    unsigned u = __float_as_uint(f);
    u += 0x7FFFu + ((u >> 16) & 1u);
    return (unsigned short)(u >> 16);
}

// ---------------------------------------------------------------------------
// 1) Projection GEMM: [N x 128] @ [128 x 256] -> xl(bf16) | xr(fp32).
//    R5 col tiling (64 col-groups x 4 cols, dense 16B W lanes, 4x W dup —
//    R6/R9 showed widening or more row-groups doubles W L2 traffic: don't).
//    NO LDS: a wave = one row-group, so x reads are wave-uniform ->
//    readfirstlane-forced scalar base => broadcast/scalar loads on the
//    SMEM/VMEM pipe; x tile is L1-resident.  Kills the LDS-pipe bottleneck
//    (8 ds_read_b128/k4 per wave) that capped proj at ~67 us.
// ---------------------------------------------------------------------------
__global__ void __launch_bounds__(256)
proj_kernel(const float* __restrict__ x,
            const float* __restrict__ Wl,
            const float* __restrict__ Wr,
            unsigned short* __restrict__ xlb,
            float* __restrict__ xr, int N,
            int* __restrict__ zero_region, int zero_cnt) {
    const int tid = threadIdx.x;
    const int n0 = blockIdx.x * 32;
    const int rows = min(32, N - n0);

    // fold the CSR zero-init into this kernel (one launch saved)
    const int gz = blockIdx.x * 256 + tid;
    if (gz < zero_cnt) zero_region[gz] = 0;

    const int cg = tid & 63;   // column group: 4 consecutive cols (dense lanes)
    const int rgu = __builtin_amdgcn_readfirstlane(tid >> 6);  // wave-uniform
    const float* Wp;
    int cb;
    const bool isL = (cg < 32);
    if (isL) { Wp = Wl; cb = cg * 4; }
    else     { Wp = Wr; cb = (cg - 32) * 4; }

    // 8 wave-uniform row pointers (clamped for the ragged last block)
    const float* xrowp[8];
#pragma unroll
    for (int r = 0; r < 8; ++r)
        xrowp[r] = x + (size_t)min(n0 + rgu * 8 + r, N - 1) * IN_F;

    float4 acc[8];
#pragma unroll
    for (int r = 0; r < 8; ++r) acc[r] = make_float4(0.f, 0.f, 0.f, 0.f);

#pragma unroll 4
    for (int k = 0; k < IN_F; k += 4) {
        const float4 wv0 = *(const float4*)&Wp[(k + 0) * HC + cb];
        const float4 wv1 = *(const float4*)&Wp[(k + 1) * HC + cb];
        const float4 wv2 = *(const float4*)&Wp[(k + 2) * HC + cb];
        const float4 wv3 = *(const float4*)&Wp[(k + 3) * HC + cb];
#pragma unroll
        for (int r = 0; r < 8; ++r) {
            const float4 xv = *(const float4*)&xrowp[r][k];  // wave-uniform load
            acc[r].x += xv.x * wv0.x; acc[r].y += xv.x * wv0.y;
            acc[r].z += xv.x * wv0.z; acc[r].w += xv.x * wv0.w;
            acc[r].x += xv.y * wv1.x; acc[r].y += xv.y * wv1.y;
            acc[r].z += xv.y * wv1.z; acc[r].w += xv.y * wv1.w;
            acc[r].x += xv.z * wv2.x; acc[r].y += xv.z * wv2.y;
            acc[r].z += xv.z * wv2.z; acc[r].w += xv.z * wv2.w;
            acc[r].x += xv.w * wv3.x; acc[r].y += xv.w * wv3.y;
            acc[r].z += xv.w * wv3.z; acc[r].w += xv.w * wv3.w;
        }
    }

#pragma unroll
    for (int r = 0; r < 8; ++r) {
        const int rr = rgu * 8 + r;
        if (rr >= rows) continue;
        if (isL) {
            ushort4 p;
            p.x = f2bf(acc[r].x); p.y = f2bf(acc[r].y);
            p.z = f2bf(acc[r].z); p.w = f2bf(acc[r].w);
            *(ushort4*)&xlb[(size_t)(n0 + rr) * HC + cb] = p;
        } else {
            *(float4*)&xr[(size_t)(n0 + rr) * HC + cb] = acc[r];
        }
    }
}

// ---------------------------------------------------------------------------
// 2) CSR build
// ---------------------------------------------------------------------------
__global__ void hist_kernel(const int* __restrict__ ei, int* __restrict__ deg,
                            int E0, int Etot) {
    const int t = blockIdx.x * blockDim.x + threadIdx.x;
    if (t >= Etot) return;
    const int dst = (t < E0) ? ei[E0 + t] : (t - E0);
    atomicAdd(&deg[dst], 1);
}

__global__ void alloc_kernel(const int* __restrict__ deg,
                             int* __restrict__ start,
                             unsigned int* __restrict__ cursor, int N) {
    __shared__ int sc[256];
    __shared__ int base_s;
    const int tid = threadIdx.x;
    const int n = blockIdx.x * 256 + tid;
    const int d = (n < N) ? deg[n] : 0;
    sc[tid] = d;
    __syncthreads();
#pragma unroll
    for (int off = 1; off < 256; off <<= 1) {
        int v = (tid >= off) ? sc[tid - off] : 0;
        __syncthreads();
        sc[tid] += v;
        __syncthreads();
    }
    if (tid == 255) base_s = (int)atomicAdd(cursor, (unsigned int)sc[255]);
    __syncthreads();
    if (n < N) start[n] = base_s + sc[tid] - d;  // exclusive
}

__global__ void scatter_kernel(const int* __restrict__ ei,
                               const int* __restrict__ start,
                               int* __restrict__ fill,
                               int* __restrict__ esrc,
                               int E0, int Etot) {
    const int t = blockIdx.x * blockDim.x + threadIdx.x;
    if (t >= Etot) return;
    int src, dst;
    if (t < E0) { src = ei[t]; dst = ei[E0 + t]; }
    else        { src = dst = t - E0; }
    const int pos = start[dst] + atomicAdd(&fill[dst], 1);
    esrc[pos] = src;
}

// ---------------------------------------------------------------------------
// 3) Fused attention + softmax + aggregation (unchanged from R9 — verified).
//    One wave per node; lane l owns channels (2l, 2l+1).  bf16x2 xl gather
//    with SGPR-base addressing; DPP 4-stage reduce + ds_swizzle broadcast.
// ---------------------------------------------------------------------------
template <int CTRL>
__device__ __forceinline__ float dpp_add(float v) {
    const int t = __builtin_amdgcn_update_dpp(
        0, __float_as_int(v), CTRL, 0xF, 0xF, true);
    return v + __int_as_float(t);
}

__device__ __forceinline__ float row_sum_bcast(float c) {
    c = dpp_add<0x111>(c);  // row_shr:1
    c = dpp_add<0x112>(c);  // row_shr:2
    c = dpp_add<0x114>(c);  // row_shr:4
    c = dpp_add<0x118>(c);  // row_shr:8 -> lane15 of each 16-row = row sum
    return __int_as_float(
        __builtin_amdgcn_ds_swizzle(__float_as_int(c), 0x01F0));  // bcast lane15
}

__global__ void __launch_bounds__(256)
fused_agg_kernel(const unsigned short* __restrict__ xlb,
                 const float* __restrict__ xr,
                 const float* __restrict__ att,
                 const float* __restrict__ bias,
                 const int* __restrict__ esrc,
                 const int* __restrict__ start,
                 const int* __restrict__ deg,
                 float* __restrict__ out, int N, int EtotM1) {
    __shared__ int les_all[4][68];
    const int wid = threadIdx.x >> 6;
    const int lane = threadIdx.x & 63;
    const int n = blockIdx.x * 4 + wid;
    if (n >= N) return;
    int* les = les_all[wid];

    const int ch = lane * 2;  // channel pair; head = lane>>4 = DPP row
    const float2 xr2 = *(const float2*)&xr[(size_t)n * HC + ch];
    const float2 at2 = *(const float2*)&att[ch];
    const float au0 = at2.x * LOG2E, au1 = at2.y * LOG2E;
    const float an0 = au0 * NEG_SLOPE, an1 = au1 * NEG_SLOPE;
    const int s0 = start[n];
    const int d = deg[n];                      // >= 1 (self-loop)

    float sum = 0.f, ax = 0.f, ay = 0.f;

    for (int jb = 0; jb < d; jb += 64) {
        const int cnt = min(64, d - jb);
        les[lane] = esrc[min(s0 + jb + lane, EtotM1)];  // clamped: valid id
        if (lane < 4) les[64 + lane] = 0;               // pad for prefetch

        const int sA0 = __builtin_amdgcn_readfirstlane(les[0]);
        const int sB0 = __builtin_amdgcn_readfirstlane(les[1]);
        unsigned pkA = *(const unsigned*)&xlb[(size_t)sA0 * HC + ch];
        unsigned pkB = *(const unsigned*)&xlb[(size_t)sB0 * HC + ch];

        int j = 0;
        for (; j + 1 < cnt; j += 2) {
            const int sC = __builtin_amdgcn_readfirstlane(les[j + 2]);
            const int sD = __builtin_amdgcn_readfirstlane(les[j + 3]);
            const unsigned pkC = *(const unsigned*)&xlb[(size_t)sC * HC + ch];
            const unsigned pkD = *(const unsigned*)&xlb[(size_t)sD * HC + ch];

            // edge A
            {
                const float vx = __uint_as_float(pkA << 16);
                const float vy = __uint_as_float(pkA & 0xFFFF0000u);
                const float sx = vx + xr2.x;
                const float sy = vy + xr2.y;
                float c = ((sx > 0.f) ? au0 : an0) * sx;
                c = fmaf(((sy > 0.f) ? au1 : an1), sy, c);
                const float p = exp2f(row_sum_bcast(c));
                sum += p;
                ax = fmaf(p, vx, ax);
                ay = fmaf(p, vy, ay);
            }
            // edge B
            {
                const float vx = __uint_as_float(pkB << 16);
                const float vy = __uint_as_float(pkB & 0xFFFF0000u);
                const float sx = vx + xr2.x;
                const float sy = vy + xr2.y;
                float c = ((sx > 0.f) ? au0 : an0) * sx;
                c = fmaf(((sy > 0.f) ? au1 : an1), sy, c);
                const float p = exp2f(row_sum_bcast(c));
                sum += p;
                ax = fmaf(p, vx, ax);
                ay = fmaf(p, vy, ay);
            }
            pkA = pkC; pkB = pkD;
        }
        if (j < cnt) {  // tail edge
            const float vx = __uint_as_float(pkA << 16);
            const float vy = __uint_as_float(pkA & 0xFFFF0000u);
            const float sx = vx + xr2.x;
            const float sy = vy + xr2.y;
            float c = ((sx > 0.f) ? au0 : an0) * sx;
            c = fmaf(((sy > 0.f) ? au1 : an1), sy, c);
            const float p = exp2f(row_sum_bcast(c));
            sum += p;
            ax = fmaf(p, vx, ax);
            ay = fmaf(p, vy, ay);
        }
    }
    const float inv = 1.f / (sum + 1e-16f);
    const float2 b2 = *(const float2*)&bias[ch];
    float2 o;
    o.x = fmaf(ax, inv, b2.x);
    o.y = fmaf(ay, inv, b2.y);
    *(float2*)&out[(size_t)n * HC + ch] = o;
}

// ---------------------------------------------------------------------------
extern "C" void kernel_launch(void* const* d_in, const int* in_sizes, int n_in,
                              void* d_out, int out_size, void* d_ws, size_t ws_size,
                              hipStream_t stream) {
    const float* x    = (const float*)d_in[0];
    const int*   ei   = (const int*)d_in[1];   // harness delivers int inputs as int32
    const float* Wl   = (const float*)d_in[2];
    const float* Wr   = (const float*)d_in[3];
    const float* att  = (const float*)d_in[4];
    const float* bias = (const float*)d_in[5];
    float* out        = (float*)d_out;

    const int N    = in_sizes[0] / IN_F;   // 50000
    const int E0   = in_sizes[1] / 2;      // 800000
    const int Etot = E0 + N;               // 850000

    char* base = (char*)d_ws;
    unsigned short* xlb = (unsigned short*)base; base += (size_t)N * HC * sizeof(unsigned short);
    float* xr   = (float*)base;        base += (size_t)N * HC * sizeof(float);
    int*   esrc = (int*)base;          base += (size_t)Etot * sizeof(int);
    // contiguous zero region: deg | fill | cursor
    int*   deg  = (int*)base;          base += (size_t)N * sizeof(int);
    int*   fill = (int*)base;          base += (size_t)N * sizeof(int);
    unsigned int* cursor = (unsigned int*)base; base += sizeof(unsigned int);
    int*   strt = (int*)base;

    proj_kernel<<<(N + 31) / 32, 256, 0, stream>>>(x, Wl, Wr, xlb, xr, N,
                                                   deg, 2 * N + 1);
    hist_kernel<<<(Etot + 255) / 256, 256, 0, stream>>>(ei, deg, E0, Etot);
    alloc_kernel<<<(N + 255) / 256, 256, 0, stream>>>(deg, strt, cursor, N);
    scatter_kernel<<<(Etot + 255) / 256, 256, 0, stream>>>(ei, strt, fill, esrc, E0, Etot);

    fused_agg_kernel<<<(N + 3) / 4, 256, 0, stream>>>(xlb, xr, att, bias, esrc, strt, deg,
                                                      out, N, Etot - 1);
}

// Round 11
// 249.103 us; speedup vs baseline: 1.1506x; 1.1303x over previous
//
#include <hip/hip_runtime.h>
#include <math.h>

#define IN_F 128
#define OUT_F 32
#define HEADS 4
#define HC 128  // HEADS*OUT_F
#define NEG_SLOPE 0.2f
#define LOG2E 1.44269504088896f
#define ALD 136  // padded LDS A-row stride in bf16 (+8 breaks bank alignment)

typedef short bf16x8 __attribute__((ext_vector_type(8)));
typedef float f32x4 __attribute__((ext_vector_type(4)));

__device__ __forceinline__ unsigned short f2bf(float f) {  // RNE fp32->bf16
    unsigned u = __float_as_uint(f);
    u += 0x7FFFu + ((u >> 16) & 1u);
    return (unsigned short)(u >> 16);
}

// ---------------------------------------------------------------------------
// 0) prep: Wt[n][k] = bf16(concat(Wl,Wr)[k][n])  (B-operand, 64 KB, L2-hot)
//    + zero deg|fill|cursor (must precede proj's folded hist atomics).
// ---------------------------------------------------------------------------
__global__ void __launch_bounds__(256)
prep_kernel(const float* __restrict__ Wl, const float* __restrict__ Wr,
            unsigned short* __restrict__ Wt,
            int* __restrict__ zero_region, int zero_cnt) {
    const int t0 = blockIdx.x * 256 + threadIdx.x;
    const int stride = gridDim.x * 256;
    for (int i = t0; i < 256 * IN_F; i += stride) {
        const int n = i >> 7, k = i & 127;
        const float v = (n < 128) ? Wl[k * 128 + n] : Wr[k * 128 + (n - 128)];
        Wt[i] = f2bf(v);
    }
    for (int i = t0; i < zero_cnt; i += stride) zero_region[i] = 0;
}

// ---------------------------------------------------------------------------
// 1) Projection via MFMA bf16: [N x 128] @ [128 x 256] -> xl(bf16) | xr(fp32).
//    64-row tile / block (4 waves x 16 rows).  A staged bf16 in LDS; B frags
//    from Wt (global, L2-hot).  16 col-tiles x 4 k-steps = 64 MFMAs / wave.
//    C/D layout: col=lane&15, row=(lane>>4)*4+reg (m89-verified).
//    Grid-stride hist prologue (deg zeroed in prep) replaces hist_kernel.
// ---------------------------------------------------------------------------
__global__ void __launch_bounds__(256)
proj_kernel(const float* __restrict__ x,
            const unsigned short* __restrict__ Wt,
            unsigned short* __restrict__ xlb,
            float* __restrict__ xr, int N,
            const int* __restrict__ ei, int* __restrict__ deg,
            int E0, int Etot) {
    __shared__ unsigned short As[64 * ALD];
    const int tid = threadIdx.x;

    // folded histogram: atomics overlap the staging + MFMA below
    for (int t = blockIdx.x * 256 + tid; t < Etot; t += gridDim.x * 256) {
        const int dst = (t < E0) ? ei[E0 + t] : (t - E0);
        atomicAdd(&deg[dst], 1);
    }

    const int n0 = blockIdx.x * 64;
#pragma unroll
    for (int q = 0; q < 8; ++q) {
        const int idx = q * 256 + tid;       // float4 index over 64x128 tile
        const int row = idx >> 5;
        const int col4 = (idx & 31) * 4;
        const float4 v = *(const float4*)&x[(size_t)min(n0 + row, N - 1) * IN_F + col4];
        ushort4 p;
        p.x = f2bf(v.x); p.y = f2bf(v.y); p.z = f2bf(v.z); p.w = f2bf(v.w);
        *(ushort4*)&As[row * ALD + col4] = p;
    }
    __syncthreads();

    const int w = tid >> 6, lane = tid & 63;
    const int lm = lane & 15, lg = lane >> 4;

    bf16x8 af[4];
#pragma unroll
    for (int kk = 0; kk < 4; ++kk)
        af[kk] = *(const bf16x8*)&As[(w * 16 + lm) * ALD + kk * 32 + lg * 8];

    f32x4 acc[16];
#pragma unroll
    for (int c = 0; c < 16; ++c) acc[c] = (f32x4){0.f, 0.f, 0.f, 0.f};

#pragma unroll
    for (int c = 0; c < 16; ++c) {
#pragma unroll
        for (int kk = 0; kk < 4; ++kk) {
            const bf16x8 bf = *(const bf16x8*)&Wt[(size_t)(c * 16 + lm) * 128 + kk * 32 + lg * 8];
            acc[c] = __builtin_amdgcn_mfma_f32_16x16x32_bf16(af[kk], bf, acc[c], 0, 0, 0);
        }
    }

    const int rbase = n0 + w * 16 + lg * 4;
#pragma unroll
    for (int c = 0; c < 16; ++c) {
#pragma unroll
        for (int r = 0; r < 4; ++r) {
            const int R = rbase + r;
            if (R >= N) continue;
            const int C = c * 16 + lm;
            if (c < 8) xlb[(size_t)R * HC + C] = f2bf(acc[c][r]);
            else       xr[(size_t)R * HC + (C - 128)] = acc[c][r];
        }
    }
}

// ---------------------------------------------------------------------------
// 2) CSR build (hist folded into proj; zero folded into prep)
// ---------------------------------------------------------------------------
__global__ void alloc_kernel(const int* __restrict__ deg,
                             int* __restrict__ start,
                             unsigned int* __restrict__ cursor, int N) {
    __shared__ int sc[256];
    __shared__ int base_s;
    const int tid = threadIdx.x;
    const int n = blockIdx.x * 256 + tid;
    const int d = (n < N) ? deg[n] : 0;
    sc[tid] = d;
    __syncthreads();
#pragma unroll
    for (int off = 1; off < 256; off <<= 1) {
        int v = (tid >= off) ? sc[tid - off] : 0;
        __syncthreads();
        sc[tid] += v;
        __syncthreads();
    }
    if (tid == 255) base_s = (int)atomicAdd(cursor, (unsigned int)sc[255]);
    __syncthreads();
    if (n < N) start[n] = base_s + sc[tid] - d;  // exclusive
}

__global__ void scatter_kernel(const int* __restrict__ ei,
                               const int* __restrict__ start,
                               int* __restrict__ fill,
                               int* __restrict__ esrc,
                               int E0, int Etot) {
    const int t = blockIdx.x * blockDim.x + threadIdx.x;
    if (t >= Etot) return;
    int src, dst;
    if (t < E0) { src = ei[t]; dst = ei[E0 + t]; }
    else        { src = dst = t - E0; }
    const int pos = start[dst] + atomicAdd(&fill[dst], 1);
    esrc[pos] = src;
}

// ---------------------------------------------------------------------------
// 3) Fused attention + softmax + aggregation (unchanged — verified R9/R10).
//    One wave per node; lane l owns channels (2l, 2l+1).  bf16x2 xl gather
//    with SGPR-base addressing; DPP 4-stage reduce + ds_swizzle broadcast.
// ---------------------------------------------------------------------------
template <int CTRL>
__device__ __forceinline__ float dpp_add(float v) {
    const int t = __builtin_amdgcn_update_dpp(
        0, __float_as_int(v), CTRL, 0xF, 0xF, true);
    return v + __int_as_float(t);
}

__device__ __forceinline__ float row_sum_bcast(float c) {
    c = dpp_add<0x111>(c);  // row_shr:1
    c = dpp_add<0x112>(c);  // row_shr:2
    c = dpp_add<0x114>(c);  // row_shr:4
    c = dpp_add<0x118>(c);  // row_shr:8 -> lane15 of each 16-row = row sum
    return __int_as_float(
        __builtin_amdgcn_ds_swizzle(__float_as_int(c), 0x01F0));  // bcast lane15
}

__global__ void __launch_bounds__(256)
fused_agg_kernel(const unsigned short* __restrict__ xlb,
                 const float* __restrict__ xr,
                 const float* __restrict__ att,
                 const float* __restrict__ bias,
                 const int* __restrict__ esrc,
                 const int* __restrict__ start,
                 const int* __restrict__ deg,
                 float* __restrict__ out, int N, int EtotM1) {
    __shared__ int les_all[4][68];
    const int wid = threadIdx.x >> 6;
    const int lane = threadIdx.x & 63;
    const int n = blockIdx.x * 4 + wid;
    if (n >= N) return;
    int* les = les_all[wid];

    const int ch = lane * 2;  // channel pair; head = lane>>4 = DPP row
    const float2 xr2 = *(const float2*)&xr[(size_t)n * HC + ch];
    const float2 at2 = *(const float2*)&att[ch];
    const float au0 = at2.x * LOG2E, au1 = at2.y * LOG2E;
    const float an0 = au0 * NEG_SLOPE, an1 = au1 * NEG_SLOPE;
    const int s0 = start[n];
    const int d = deg[n];                      // >= 1 (self-loop)

    float sum = 0.f, ax = 0.f, ay = 0.f;

    for (int jb = 0; jb < d; jb += 64) {
        const int cnt = min(64, d - jb);
        les[lane] = esrc[min(s0 + jb + lane, EtotM1)];  // clamped: valid id
        if (lane < 4) les[64 + lane] = 0;               // pad for prefetch

        const int sA0 = __builtin_amdgcn_readfirstlane(les[0]);
        const int sB0 = __builtin_amdgcn_readfirstlane(les[1]);
        unsigned pkA = *(const unsigned*)&xlb[(size_t)sA0 * HC + ch];
        unsigned pkB = *(const unsigned*)&xlb[(size_t)sB0 * HC + ch];

        int j = 0;
        for (; j + 1 < cnt; j += 2) {
            const int sC = __builtin_amdgcn_readfirstlane(les[j + 2]);
            const int sD = __builtin_amdgcn_readfirstlane(les[j + 3]);
            const unsigned pkC = *(const unsigned*)&xlb[(size_t)sC * HC + ch];
            const unsigned pkD = *(const unsigned*)&xlb[(size_t)sD * HC + ch];

            // edge A
            {
                const float vx = __uint_as_float(pkA << 16);
                const float vy = __uint_as_float(pkA & 0xFFFF0000u);
                const float sx = vx + xr2.x;
                const float sy = vy + xr2.y;
                float c = ((sx > 0.f) ? au0 : an0) * sx;
                c = fmaf(((sy > 0.f) ? au1 : an1), sy, c);
                const float p = exp2f(row_sum_bcast(c));
                sum += p;
                ax = fmaf(p, vx, ax);
                ay = fmaf(p, vy, ay);
            }
            // edge B
            {
                const float vx = __uint_as_float(pkB << 16);
                const float vy = __uint_as_float(pkB & 0xFFFF0000u);
                const float sx = vx + xr2.x;
                const float sy = vy + xr2.y;
                float c = ((sx > 0.f) ? au0 : an0) * sx;
                c = fmaf(((sy > 0.f) ? au1 : an1), sy, c);
                const float p = exp2f(row_sum_bcast(c));
                sum += p;
                ax = fmaf(p, vx, ax);
                ay = fmaf(p, vy, ay);
            }
            pkA = pkC; pkB = pkD;
        }
        if (j < cnt) {  // tail edge
            const float vx = __uint_as_float(pkA << 16);
            const float vy = __uint_as_float(pkA & 0xFFFF0000u);
            const float sx = vx + xr2.x;
            const float sy = vy + xr2.y;
            float c = ((sx > 0.f) ? au0 : an0) * sx;
            c = fmaf(((sy > 0.f) ? au1 : an1), sy, c);
            const float p = exp2f(row_sum_bcast(c));
            sum += p;
            ax = fmaf(p, vx, ax);
            ay = fmaf(p, vy, ay);
        }
    }
    const float inv = 1.f / (sum + 1e-16f);
    const float2 b2 = *(const float2*)&bias[ch];
    float2 o;
    o.x = fmaf(ax, inv, b2.x);
    o.y = fmaf(ay, inv, b2.y);
    *(float2*)&out[(size_t)n * HC + ch] = o;
}

// ---------------------------------------------------------------------------
extern "C" void kernel_launch(void* const* d_in, const int* in_sizes, int n_in,
                              void* d_out, int out_size, void* d_ws, size_t ws_size,
                              hipStream_t stream) {
    const float* x    = (const float*)d_in[0];
    const int*   ei   = (const int*)d_in[1];   // harness delivers int inputs as int32
    const float* Wl   = (const float*)d_in[2];
    const float* Wr   = (const float*)d_in[3];
    const float* att  = (const float*)d_in[4];
    const float* bias = (const float*)d_in[5];
    float* out        = (float*)d_out;

    const int N    = in_sizes[0] / IN_F;   // 50000
    const int E0   = in_sizes[1] / 2;      // 800000
    const int Etot = E0 + N;               // 850000

    char* base = (char*)d_ws;
    unsigned short* xlb = (unsigned short*)base; base += (size_t)N * HC * sizeof(unsigned short);
    float* xr   = (float*)base;        base += (size_t)N * HC * sizeof(float);
    int*   esrc = (int*)base;          base += (size_t)Etot * sizeof(int);
    // contiguous zero region: deg | fill | cursor
    int*   deg  = (int*)base;          base += (size_t)N * sizeof(int);
    int*   fill = (int*)base;          base += (size_t)N * sizeof(int);
    unsigned int* cursor = (unsigned int*)base; base += sizeof(unsigned int);
    int*   strt = (int*)base;          base += (size_t)N * sizeof(int);
    unsigned short* Wt = (unsigned short*)base;

    prep_kernel<<<400, 256, 0, stream>>>(Wl, Wr, Wt, deg, 2 * N + 1);
    proj_kernel<<<(N + 63) / 64, 256, 0, stream>>>(x, Wt, xlb, xr, N,
                                                   ei, deg, E0, Etot);
    alloc_kernel<<<(N + 255) / 256, 256, 0, stream>>>(deg, strt, cursor, N);
    scatter_kernel<<<(Etot + 255) / 256, 256, 0, stream>>>(ei, strt, fill, esrc, E0, Etot);

    fused_agg_kernel<<<(N + 3) / 4, 256, 0, stream>>>(xlb, xr, att, bias, esrc, strt, deg,
                                                      out, N, Etot - 1);
}